// Round 1
// baseline (770.839 us; speedup 1.0000x reference)
//
#include <hip/hip_runtime.h>
#include <hip/hip_bf16.h>

#define B_ 128
#define T_ 512
#define N_ 256
#define H_ 1024

typedef unsigned short u16;
typedef __attribute__((ext_vector_type(8))) __bf16 bf16x8;
typedef __attribute__((ext_vector_type(4))) float f32x4;

__device__ __forceinline__ u16 f2bf(float f) {
    unsigned u = __float_as_uint(f);
    u = (u + 0x7FFFu + ((u >> 16) & 1u)) >> 16;
    return (u16)u;
}

__device__ __forceinline__ void g2l16(const void* g, void* l) {
    __builtin_amdgcn_global_load_lds(
        (const __attribute__((address_space(1))) void*)g,
        (__attribute__((address_space(3))) void*)l,
        16, 0, 0);
}

// ---------------------------------------------------------------------------
// GEMM: C[M,Nc] = act( A[M,K](bf16) @ Bt[Nc,K]^T(bf16) + bias[row>>bshift][col] )
// 128x128 tile, BK=64, 256 threads (4 waves, 2x2), mfma 16x16x32 bf16.
// ---------------------------------------------------------------------------
template<int ACT, int OUTF32>
__global__ __launch_bounds__(256) void gemm_bt(
    const u16* __restrict__ A, const u16* __restrict__ Bt,
    float* __restrict__ Cf, u16* __restrict__ Cb,
    const float* __restrict__ bias,
    int M, int Nc, int K, int bshift)
{
    __shared__ u16 lA[128 * 64];
    __shared__ u16 lB[128 * 64];
    const int tid = threadIdx.x;
    const int wave = tid >> 6, lane = tid & 63;
    const int l16 = lane & 15, lh = lane >> 4;
    const int wm = wave >> 1, wn = wave & 1;
    const long m0 = (long)blockIdx.x * 128;
    const long n0 = (long)blockIdx.y * 128;

    f32x4 acc[4][4] = {};

    for (int k0 = 0; k0 < K; k0 += 64) {
#pragma unroll
        for (int j = 0; j < 4; ++j) {
            int c = j * 256 + tid;
            int row = c >> 3, col = (c & 7) << 3;   // 8 chunks of 16B per 64-elem row
            g2l16(A  + (m0 + row) * (size_t)K + k0 + col, &lA[(size_t)(j * 256 + (wave << 6)) * 8]);
            g2l16(Bt + (n0 + row) * (size_t)K + k0 + col, &lB[(size_t)(j * 256 + (wave << 6)) * 8]);
        }
        __syncthreads();   // drains vmcnt for global_load_lds, then barrier
#pragma unroll
        for (int s = 0; s < 2; ++s) {
            bf16x8 af[4], bfr[4];
#pragma unroll
            for (int mi = 0; mi < 4; ++mi)
                af[mi] = *(const bf16x8*)&lA[((wm << 6) + (mi << 4) + l16) * 64 + s * 32 + (lh << 3)];
#pragma unroll
            for (int ni = 0; ni < 4; ++ni)
                bfr[ni] = *(const bf16x8*)&lB[((wn << 6) + (ni << 4) + l16) * 64 + s * 32 + (lh << 3)];
#pragma unroll
            for (int mi = 0; mi < 4; ++mi)
#pragma unroll
                for (int ni = 0; ni < 4; ++ni)
                    acc[mi][ni] = __builtin_amdgcn_mfma_f32_16x16x32_bf16(af[mi], bfr[ni], acc[mi][ni], 0, 0, 0);
        }
        __syncthreads();
    }

    // Epilogue. Verified C/D layout: col = lane&15, row = (lane>>4)*4 + reg.
#pragma unroll
    for (int mi = 0; mi < 4; ++mi) {
#pragma unroll
        for (int ni = 0; ni < 4; ++ni) {
            long rbase = m0 + (wm << 6) + (mi << 4) + (lh << 2);
            long col   = n0 + (wn << 6) + (ni << 4) + l16;
#pragma unroll
            for (int r = 0; r < 4; ++r) {
                long row = rbase + r;
                float v = acc[mi][ni][r];
                if (bias) v += bias[(size_t)(row >> bshift) * Nc + col];
                if (ACT) v = 1.0f / (1.0f + __expf(-v));
                if (OUTF32) Cf[(size_t)row * Nc + col] = v;
                else        Cb[(size_t)row * Nc + col] = f2bf(v);
            }
        }
    }
}

// x[B,T,N] f32 -> h[B,N,T] bf16 (transpose last two dims, per batch)
__global__ void k_tr_x(const float* __restrict__ x, u16* __restrict__ h) {
    __shared__ float tile[32][33];
    int b = blockIdx.z;
    int n0 = blockIdx.x * 32, t0 = blockIdx.y * 32;
    int tx = threadIdx.x, ty = threadIdx.y;
    const float* xb = x + (size_t)b * T_ * N_;
#pragma unroll
    for (int i = 0; i < 4; ++i)
        tile[ty + 8 * i][tx] = xb[(size_t)(t0 + ty + 8 * i) * N_ + n0 + tx];
    __syncthreads();
    u16* hb = h + (size_t)b * N_ * T_;
#pragma unroll
    for (int i = 0; i < 4; ++i)
        hb[(size_t)(n0 + ty + 8 * i) * T_ + t0 + tx] = f2bf(tile[tx][ty + 8 * i]);
}

// p[B,N,T] bf16 -> q[B,T,N] bf16
__global__ void k_tr_p(const u16* __restrict__ p, u16* __restrict__ q) {
    __shared__ u16 tile[32][33];
    int b = blockIdx.z;
    int t0 = blockIdx.x * 32, n0 = blockIdx.y * 32;
    int tx = threadIdx.x, ty = threadIdx.y;
    const u16* pb = p + (size_t)b * N_ * T_;
#pragma unroll
    for (int i = 0; i < 4; ++i)
        tile[ty + 8 * i][tx] = pb[(size_t)(n0 + ty + 8 * i) * T_ + t0 + tx];
    __syncthreads();
    u16* qb = q + (size_t)b * T_ * N_;
#pragma unroll
    for (int i = 0; i < 4; ++i)
        qb[(size_t)(t0 + ty + 8 * i) * N_ + n0 + tx] = tile[tx][ty + 8 * i];
}

// s1[b,t] = sum_n x[b,t,n]  (one wave per row, float4 loads)
__global__ void k_rowsum(const float* __restrict__ x, float* __restrict__ s1) {
    int row = blockIdx.x * 4 + (threadIdx.x >> 6);
    int lane = threadIdx.x & 63;
    const float4 v = *(const float4*)(x + (size_t)row * N_ + lane * 4);
    float s = v.x + v.y + v.z + v.w;
#pragma unroll
    for (int o = 32; o; o >>= 1) s += __shfl_down(s, o, 64);
    if (lane == 0) s1[row] = s;
}

// Wt[c][r] = bf16( Wr[r][c] - Wl[r][c]/255 )   (Wl nullable -> plain transpose-cast)
__global__ void k_combine_t(const float* __restrict__ Wr, const float* __restrict__ Wl,
                            u16* __restrict__ Wt, int R, int C) {
    __shared__ float tile[32][33];
    int r0 = blockIdx.x * 32, c0 = blockIdx.y * 32;
    int tx = threadIdx.x, ty = threadIdx.y;
#pragma unroll
    for (int i = 0; i < 4; ++i) {
        int r = r0 + ty + 8 * i;
        float v = Wr[(size_t)r * C + c0 + tx];
        if (Wl) v -= Wl[(size_t)r * C + c0 + tx] * (1.0f / 255.0f);
        tile[ty + 8 * i][tx] = v;
    }
    __syncthreads();
#pragma unroll
    for (int i = 0; i < 4; ++i)
        Wt[(size_t)(c0 + ty + 8 * i) * R + r0 + tx] = f2bf(tile[tx][ty + 8 * i]);
}

// Rank-1 terms for SAGE1: t1b1[b,h] = s1@Wl1/255 + b1 ; u1s[b,h] = bf16(u1/255),
// u1 = sum_n h1[b,n,h] = accl + accr + 256*b1.
__global__ __launch_bounds__(256) void k_vec1(
    const float* __restrict__ s1, const float* __restrict__ Wl1,
    const float* __restrict__ Wr1, const float* __restrict__ b1,
    float* __restrict__ t1b1, u16* __restrict__ u1s)
{
    __shared__ float sm[16 * 512];
    int h = blockIdx.x * 256 + threadIdx.x;
    int b0 = blockIdx.y * 16;
    for (int i = threadIdx.x; i < 16 * 512; i += 256)
        sm[i] = s1[(size_t)b0 * 512 + i];
    __syncthreads();
    float accl[16] = {}, accr[16] = {};
    for (int t = 0; t < 512; ++t) {
        float wl = Wl1[(size_t)t * H_ + h];
        float wr = Wr1[(size_t)t * H_ + h];
#pragma unroll
        for (int bb = 0; bb < 16; ++bb) {
            float sv = sm[bb * 512 + t];
            accl[bb] += sv * wl;
            accr[bb] += sv * wr;
        }
    }
    float bv = b1[h];
#pragma unroll
    for (int bb = 0; bb < 16; ++bb) {
        float t1 = accl[bb] * (1.0f / 255.0f);
        t1b1[(size_t)(b0 + bb) * H_ + h] = t1 + bv;
        float u1 = accl[bb] + accr[bb] + 256.0f * bv;
        u1s[(size_t)(b0 + bb) * H_ + h] = f2bf(u1 * (1.0f / 255.0f));
    }
}

extern "C" void kernel_launch(void* const* d_in, const int* in_sizes, int n_in,
                              void* d_out, int out_size, void* d_ws, size_t ws_size,
                              hipStream_t stream)
{
    const float* x   = (const float*)d_in[0];
    const float* Wl1 = (const float*)d_in[1];
    const float* Wr1 = (const float*)d_in[2];
    const float* b1  = (const float*)d_in[3];
    const float* Wl2 = (const float*)d_in[4];
    const float* Wr2 = (const float*)d_in[5];
    const float* b2  = (const float*)d_in[6];
    const float* W1a = (const float*)d_in[7];
    const float* W1b = (const float*)d_in[8];
    const float* W2a = (const float*)d_in[9];
    const float* W2b = (const float*)d_in[10];
    float* out = (float*)d_out;

    char* ws = (char*)d_ws;
    size_t off = 0;
    auto alloc = [&](size_t bytes) -> char* {
        char* p = ws + off;
        off += (bytes + 255) & ~(size_t)255;
        return p;
    };

    const size_t BN = (size_t)B_ * N_;   // 32768
    const size_t BT = (size_t)B_ * T_;   // 65536

    u16* h_bf  = (u16*)alloc(BN * T_ * 2);   // 33.5MB; reused by p after G2
    u16* h1_bf = (u16*)alloc(BN * H_ * 2);   // 67MB;  reused by q after G2
    u16* h2_bf = (u16*)alloc(BN * H_ * 2);   // 67MB;  reused by r after G3
    u16* g_bf  = (u16*)alloc(BN * H_ * 2);   // 67MB
    u16* W1t   = (u16*)alloc((size_t)T_ * H_ * 2);
    u16* W2t   = (u16*)alloc((size_t)H_ * H_ * 2);
    u16* Wl2t  = (u16*)alloc((size_t)H_ * H_ * 2);
    u16* W1at  = (u16*)alloc((size_t)H_ * H_ * 2);
    u16* W1bt  = (u16*)alloc((size_t)T_ * H_ * 2);
    u16* W2at  = (u16*)alloc((size_t)N_ * N_ * 2);
    u16* W2bt  = (u16*)alloc((size_t)N_ * H_ * 2);
    float* s1   = (float*)alloc(BT * 4);
    float* t1b1 = (float*)alloc((size_t)B_ * H_ * 4);
    float* t2b2 = (float*)alloc((size_t)B_ * H_ * 4);
    u16*   u1s  = (u16*)alloc((size_t)B_ * H_ * 2);

    u16* p_bf = h_bf;    // [B,N,T] post-sigmoid, h dead after G1
    u16* q_bf = h1_bf;   // [B,T,N], h1 dead after G2
    u16* r_bf = h2_bf;   // [B,T,N*? -> BT x 256], h2 dead after G3

    dim3 blk32(32, 8);

    // prep
    k_tr_x<<<dim3(N_ / 32, T_ / 32, B_), blk32, 0, stream>>>(x, h_bf);
    k_rowsum<<<BT / 4, 256, 0, stream>>>(x, s1);
    k_combine_t<<<dim3(T_ / 32, H_ / 32), blk32, 0, stream>>>(Wr1, Wl1, W1t, T_, H_);
    k_combine_t<<<dim3(H_ / 32, H_ / 32), blk32, 0, stream>>>(Wr2, Wl2, W2t, H_, H_);
    k_combine_t<<<dim3(H_ / 32, H_ / 32), blk32, 0, stream>>>(Wl2, nullptr, Wl2t, H_, H_);
    k_combine_t<<<dim3(H_ / 32, H_ / 32), blk32, 0, stream>>>(W1a, nullptr, W1at, H_, H_);
    k_combine_t<<<dim3(H_ / 32, T_ / 32), blk32, 0, stream>>>(W1b, nullptr, W1bt, H_, T_);
    k_combine_t<<<dim3(N_ / 32, N_ / 32), blk32, 0, stream>>>(W2a, nullptr, W2at, N_, N_);
    k_combine_t<<<dim3(N_ / 32, H_ / 32), blk32, 0, stream>>>(W2b, nullptr, W2bt, N_, H_);
    k_vec1<<<dim3(H_ / 256, B_ / 16), 256, 0, stream>>>(s1, Wl1, Wr1, b1, t1b1, u1s);
    // t2b2 = (u1/255) @ Wl2 + b2   (M=128 GEMM; bshift=31 -> bias row 0 = b2 broadcast)
    gemm_bt<0, 1><<<dim3(1, H_ / 128), 256, 0, stream>>>(u1s, Wl2t, t2b2, nullptr, b2, B_, H_, H_, 31);

    // main chain
    gemm_bt<0, 0><<<dim3(BN / 128, H_ / 128), 256, 0, stream>>>(h_bf, W1t, nullptr, h1_bf, t1b1, (int)BN, H_, T_, 8);
    gemm_bt<0, 0><<<dim3(BN / 128, H_ / 128), 256, 0, stream>>>(h1_bf, W2t, nullptr, h2_bf, t2b2, (int)BN, H_, H_, 8);
    gemm_bt<0, 0><<<dim3(BN / 128, H_ / 128), 256, 0, stream>>>(h2_bf, W1at, nullptr, g_bf, nullptr, (int)BN, H_, H_, 0);
    gemm_bt<1, 0><<<dim3(BN / 128, T_ / 128), 256, 0, stream>>>(g_bf, W1bt, nullptr, p_bf, nullptr, (int)BN, T_, H_, 0);
    k_tr_p<<<dim3(T_ / 32, N_ / 32, B_), blk32, 0, stream>>>(p_bf, q_bf);
    gemm_bt<0, 0><<<dim3(BT / 128, N_ / 128), 256, 0, stream>>>(q_bf, W2at, nullptr, r_bf, nullptr, (int)BT, N_, N_, 0);
    gemm_bt<1, 1><<<dim3(BT / 128, H_ / 128), 256, 0, stream>>>(r_bf, W2bt, out, nullptr, nullptr, (int)BT, H_, N_, 31);
}

// Round 2
// 669.634 us; speedup vs baseline: 1.1511x; 1.1511x over previous
//
#include <hip/hip_runtime.h>
#include <hip/hip_bf16.h>

#define B_ 128
#define T_ 512
#define N_ 256
#define H_ 1024

typedef unsigned short u16;
typedef __attribute__((ext_vector_type(8))) __bf16 bf16x8;
typedef __attribute__((ext_vector_type(4))) float f32x4;

__device__ __forceinline__ u16 f2bf(float f) {
    unsigned u = __float_as_uint(f);
    u = (u + 0x7FFFu + ((u >> 16) & 1u)) >> 16;
    return (u16)u;
}

__device__ __forceinline__ void g2l16(const void* g, void* l) {
    __builtin_amdgcn_global_load_lds(
        (const __attribute__((address_space(1))) void*)g,
        (__attribute__((address_space(3))) void*)l,
        16, 0, 0);
}

// ===========================================================================
// 256x256-tile 8-wave phase-pipelined GEMM with counted vmcnt (T1+T2+T3+T4+T5)
// C[M,Nc] = act( A[M,K](bf16) @ Bt[Nc,K]^T(bf16) + bias[row>>bshift][col] )
// LDS layout per buffer: A[2ks][256][32], B[2ks][256][32]  (ks-major), 128 KiB.
// Slot swizzle: 16B-slot ^= (row>>1)&3  (both sides; linear global_load_lds dest).
// Schedule/tile: P0(ks0,mi0-3: 8 ds_read + stage A-ks0'), P1(ks0,mi4-7: 4 + B-ks0'),
//   gate vmcnt(4); P2(ks1,mi0-3: 8 + A-ks1'), P3(ks1,mi4-7: 4 + B-ks1'), gate vmcnt(4).
// Steady state: gate drains exactly the 4 issues the next phase reads.
// ===========================================================================
#define LBUF 32768u
#define LMAT 16384u
#define LKS  8192u

#define BAR() { __builtin_amdgcn_s_barrier(); __builtin_amdgcn_sched_barrier(0); }
#define GATE(N) { asm volatile("s_waitcnt vmcnt(" #N ")" ::: "memory"); \
                  __builtin_amdgcn_s_barrier(); __builtin_amdgcn_sched_barrier(0); }
#define LD4(dst, base) { _Pragma("unroll") for (int i_ = 0; i_ < 4; ++i_) \
    dst[i_] = *(const bf16x8*)(L + (base) + i_ * 512); }
#define MF16(MB, RA, RB) { __builtin_amdgcn_s_setprio(1); \
    _Pragma("unroll") for (int mi_ = 0; mi_ < 4; ++mi_) \
    _Pragma("unroll") for (int ni_ = 0; ni_ < 4; ++ni_) \
        acc[(MB) + mi_][ni_] = __builtin_amdgcn_mfma_f32_16x16x32_bf16( \
            RA[mi_], RB[ni_], acc[(MB) + mi_][ni_], 0, 0, 0); \
    __builtin_amdgcn_s_setprio(0); }

template<int ACT, int OUTF32>
__global__ __launch_bounds__(512, 2) void gemm256(
    const u16* __restrict__ A, const u16* __restrict__ Bt,
    float* __restrict__ Cf, u16* __restrict__ Cb,
    const float* __restrict__ bias,
    int Nc, int K, int bshift, int gysh)
{
    __shared__ u16 L[65536];   // 128 KiB
    const int tid = threadIdx.x;
    const int wave = tid >> 6, lane = tid & 63;
    const int l16 = lane & 15, lh = lane >> 4;
    const int wm = wave >> 2, wn = wave & 3;

    // T1: bijective XCD swizzle (nwg % 8 == 0 for every launch below)
    const int qq = (int)gridDim.x >> 3;
    const int orig = (int)blockIdx.x;
    const int wg = (orig & 7) * qq + (orig >> 3);
    const int by = wg & ((1 << gysh) - 1), bx = wg >> gysh;
    const size_t m0 = (size_t)bx * 256, n0 = (size_t)by * 256;

    // T2 swizzle, read side: lane-constant 16B slot
    const int sx8 = (lh ^ ((l16 >> 1) & 3)) * 8;
    const unsigned aoff = (unsigned)(wm * 4096 + l16 * 32 + sx8);
    const unsigned boff = (unsigned)(LMAT + wn * 2048 + l16 * 32 + sx8);

    // staging: thread-constant source (pre-swizzled) + wave-uniform LDS dest
    const int srow = tid >> 2;                               // 0..127 (j adds 128)
    const int sslot = (tid & 3) ^ ((srow >> 1) & 3);
    const size_t jstr = (size_t)128 * K;
    const u16* gA = A + (m0 + srow) * (size_t)K + sslot * 8;
    const u16* gB = Bt + (n0 + srow) * (size_t)K + sslot * 8;
    u16* const dA0 = L + (unsigned)(wave * 512);
    u16* const dB0 = L + LMAT + (unsigned)(wave * 512);

    f32x4 acc[8][4] = {};
    const int nt = K >> 6;

    // prologue: tile0 -> buf0, issue order A-ks0, B-ks0, A-ks1, B-ks1
    g2l16(gA, dA0);             g2l16(gA + jstr, dA0 + 4096);
    g2l16(gB, dB0);             g2l16(gB + jstr, dB0 + 4096);
    g2l16(gA + 32, dA0 + LKS);  g2l16(gA + 32 + jstr, dA0 + LKS + 4096);
    g2l16(gB + 32, dB0 + LKS);  g2l16(gB + 32 + jstr, dB0 + LKS + 4096);
    GATE(4);

    for (int t = 0; t < nt - 1; ++t) {
        const unsigned ab = (t & 1) ? LBUF : 0u;
        const unsigned an = ab ^ LBUF;
        const u16* gAt = gA + (size_t)(t + 1) * 64;
        const u16* gBt = gB + (size_t)(t + 1) * 64;
        bf16x8 ra[4], ra2[4], rb0r[4], rb1r[4];
        // ---- P0: ks0, mi 0-3 ----
        LD4(ra,   ab + aoff);
        LD4(rb0r, ab + boff);
        g2l16(gAt, dA0 + an);  g2l16(gAt + jstr, dA0 + an + 4096);
        BAR();
        MF16(0, ra, rb0r);
        BAR();
        // ---- P1: ks0, mi 4-7 ----
        LD4(ra2, ab + aoff + 2048);
        g2l16(gBt, dB0 + an);  g2l16(gBt + jstr, dB0 + an + 4096);
        BAR();
        MF16(4, ra2, rb0r);
        GATE(4);
        // ---- P2: ks1, mi 0-3 ----
        LD4(ra,   ab + LKS + aoff);
        LD4(rb1r, ab + LKS + boff);
        g2l16(gAt + 32, dA0 + an + LKS);  g2l16(gAt + 32 + jstr, dA0 + an + LKS + 4096);
        BAR();
        MF16(0, ra, rb1r);
        BAR();
        // ---- P3: ks1, mi 4-7 ----
        LD4(ra2, ab + LKS + aoff + 2048);
        g2l16(gBt + 32, dB0 + an + LKS);  g2l16(gBt + 32 + jstr, dB0 + an + LKS + 4096);
        BAR();
        MF16(4, ra2, rb1r);
        GATE(4);
    }

    // peeled last tile: no staging; drain at the ks1 gate
    {
        const unsigned ab = ((nt - 1) & 1) ? LBUF : 0u;
        bf16x8 ra[4], ra2[4], rb0r[4], rb1r[4];
        LD4(ra,   ab + aoff);
        LD4(rb0r, ab + boff);
        BAR();
        MF16(0, ra, rb0r);
        BAR();
        LD4(ra2, ab + aoff + 2048);
        BAR();
        MF16(4, ra2, rb0r);
        GATE(0);
        LD4(ra,   ab + LKS + aoff);
        LD4(rb1r, ab + LKS + boff);
        BAR();
        MF16(0, ra, rb1r);
        BAR();
        LD4(ra2, ab + LKS + aoff + 2048);
        BAR();
        MF16(4, ra2, rb1r);
    }

    // epilogue: C/D layout col = lane&15, row = (lane>>4)*4 + reg
    const size_t NcS = (size_t)Nc;
#pragma unroll
    for (int mi = 0; mi < 8; ++mi) {
#pragma unroll
        for (int ni = 0; ni < 4; ++ni) {
            size_t rbase = m0 + wm * 128 + mi * 16 + lh * 4;
            size_t col   = n0 + wn * 64 + ni * 16 + l16;
#pragma unroll
            for (int rr = 0; rr < 4; ++rr) {
                size_t row = rbase + rr;
                float v = acc[mi][ni][rr];
                if (bias) v += bias[(row >> bshift) * NcS + col];
                if (ACT) v = 1.0f / (1.0f + __expf(-v));
                if (OUTF32) Cf[row * NcS + col] = v;
                else        Cb[row * NcS + col] = f2bf(v);
            }
        }
    }
}

// ---------------------------------------------------------------------------
// 128x128 2-barrier GEMM (kept only for the tiny M=128 t2b2 GEMM)
// ---------------------------------------------------------------------------
template<int ACT, int OUTF32>
__global__ __launch_bounds__(256) void gemm_bt(
    const u16* __restrict__ A, const u16* __restrict__ Bt,
    float* __restrict__ Cf, u16* __restrict__ Cb,
    const float* __restrict__ bias,
    int M, int Nc, int K, int bshift)
{
    __shared__ u16 lA[128 * 64];
    __shared__ u16 lB[128 * 64];
    const int tid = threadIdx.x;
    const int wave = tid >> 6, lane = tid & 63;
    const int l16 = lane & 15, lh = lane >> 4;
    const int wm = wave >> 1, wn = wave & 1;
    const long m0 = (long)blockIdx.x * 128;
    const long n0 = (long)blockIdx.y * 128;

    f32x4 acc[4][4] = {};

    for (int k0 = 0; k0 < K; k0 += 64) {
#pragma unroll
        for (int j = 0; j < 4; ++j) {
            int c = j * 256 + tid;
            int row = c >> 3, col = (c & 7) << 3;
            g2l16(A  + (m0 + row) * (size_t)K + k0 + col, &lA[(size_t)(j * 256 + (wave << 6)) * 8]);
            g2l16(Bt + (n0 + row) * (size_t)K + k0 + col, &lB[(size_t)(j * 256 + (wave << 6)) * 8]);
        }
        __syncthreads();
#pragma unroll
        for (int s = 0; s < 2; ++s) {
            bf16x8 af[4], bfr[4];
#pragma unroll
            for (int mi = 0; mi < 4; ++mi)
                af[mi] = *(const bf16x8*)&lA[((wm << 6) + (mi << 4) + l16) * 64 + s * 32 + (lh << 3)];
#pragma unroll
            for (int ni = 0; ni < 4; ++ni)
                bfr[ni] = *(const bf16x8*)&lB[((wn << 6) + (ni << 4) + l16) * 64 + s * 32 + (lh << 3)];
#pragma unroll
            for (int mi = 0; mi < 4; ++mi)
#pragma unroll
                for (int ni = 0; ni < 4; ++ni)
                    acc[mi][ni] = __builtin_amdgcn_mfma_f32_16x16x32_bf16(af[mi], bfr[ni], acc[mi][ni], 0, 0, 0);
        }
        __syncthreads();
    }

#pragma unroll
    for (int mi = 0; mi < 4; ++mi) {
#pragma unroll
        for (int ni = 0; ni < 4; ++ni) {
            long rbase = m0 + (wm << 6) + (mi << 4) + (lh << 2);
            long col   = n0 + (wn << 6) + (ni << 4) + l16;
#pragma unroll
            for (int r = 0; r < 4; ++r) {
                long row = rbase + r;
                float v = acc[mi][ni][r];
                if (bias) v += bias[(size_t)(row >> bshift) * Nc + col];
                if (ACT) v = 1.0f / (1.0f + __expf(-v));
                if (OUTF32) Cf[(size_t)row * Nc + col] = v;
                else        Cb[(size_t)row * Nc + col] = f2bf(v);
            }
        }
    }
}

// x[B,T,N] f32 -> h[B,N,T] bf16
__global__ void k_tr_x(const float* __restrict__ x, u16* __restrict__ h) {
    __shared__ float tile[32][33];
    int b = blockIdx.z;
    int n0 = blockIdx.x * 32, t0 = blockIdx.y * 32;
    int tx = threadIdx.x, ty = threadIdx.y;
    const float* xb = x + (size_t)b * T_ * N_;
#pragma unroll
    for (int i = 0; i < 4; ++i)
        tile[ty + 8 * i][tx] = xb[(size_t)(t0 + ty + 8 * i) * N_ + n0 + tx];
    __syncthreads();
    u16* hb = h + (size_t)b * N_ * T_;
#pragma unroll
    for (int i = 0; i < 4; ++i)
        hb[(size_t)(n0 + ty + 8 * i) * T_ + t0 + tx] = f2bf(tile[tx][ty + 8 * i]);
}

// p[B,N,T] bf16 -> q[B,T,N] bf16
__global__ void k_tr_p(const u16* __restrict__ p, u16* __restrict__ q) {
    __shared__ u16 tile[32][33];
    int b = blockIdx.z;
    int t0 = blockIdx.x * 32, n0 = blockIdx.y * 32;
    int tx = threadIdx.x, ty = threadIdx.y;
    const u16* pb = p + (size_t)b * N_ * T_;
#pragma unroll
    for (int i = 0; i < 4; ++i)
        tile[ty + 8 * i][tx] = pb[(size_t)(n0 + ty + 8 * i) * T_ + t0 + tx];
    __syncthreads();
    u16* qb = q + (size_t)b * T_ * N_;
#pragma unroll
    for (int i = 0; i < 4; ++i)
        qb[(size_t)(t0 + ty + 8 * i) * N_ + n0 + tx] = tile[tx][ty + 8 * i];
}

// s1[b,t] = sum_n x[b,t,n]
__global__ void k_rowsum(const float* __restrict__ x, float* __restrict__ s1) {
    int row = blockIdx.x * 4 + (threadIdx.x >> 6);
    int lane = threadIdx.x & 63;
    const float4 v = *(const float4*)(x + (size_t)row * N_ + lane * 4);
    float s = v.x + v.y + v.z + v.w;
#pragma unroll
    for (int o = 32; o; o >>= 1) s += __shfl_down(s, o, 64);
    if (lane == 0) s1[row] = s;
}

// Wt[c][r] = bf16( Wr[r][c] - Wl[r][c]/255 )
__global__ void k_combine_t(const float* __restrict__ Wr, const float* __restrict__ Wl,
                            u16* __restrict__ Wt, int R, int C) {
    __shared__ float tile[32][33];
    int r0 = blockIdx.x * 32, c0 = blockIdx.y * 32;
    int tx = threadIdx.x, ty = threadIdx.y;
#pragma unroll
    for (int i = 0; i < 4; ++i) {
        int r = r0 + ty + 8 * i;
        float v = Wr[(size_t)r * C + c0 + tx];
        if (Wl) v -= Wl[(size_t)r * C + c0 + tx] * (1.0f / 255.0f);
        tile[ty + 8 * i][tx] = v;
    }
    __syncthreads();
#pragma unroll
    for (int i = 0; i < 4; ++i)
        Wt[(size_t)(c0 + ty + 8 * i) * R + r0 + tx] = f2bf(tile[tx][ty + 8 * i]);
}

// Rank-1 terms for SAGE1
__global__ __launch_bounds__(256) void k_vec1(
    const float* __restrict__ s1, const float* __restrict__ Wl1,
    const float* __restrict__ Wr1, const float* __restrict__ b1,
    float* __restrict__ t1b1, u16* __restrict__ u1s)
{
    __shared__ float sm[16 * 512];
    int h = blockIdx.x * 256 + threadIdx.x;
    int b0 = blockIdx.y * 16;
    for (int i = threadIdx.x; i < 16 * 512; i += 256)
        sm[i] = s1[(size_t)b0 * 512 + i];
    __syncthreads();
    float accl[16] = {}, accr[16] = {};
    for (int t = 0; t < 512; ++t) {
        float wl = Wl1[(size_t)t * H_ + h];
        float wr = Wr1[(size_t)t * H_ + h];
#pragma unroll
        for (int bb = 0; bb < 16; ++bb) {
            float sv = sm[bb * 512 + t];
            accl[bb] += sv * wl;
            accr[bb] += sv * wr;
        }
    }
    float bv = b1[h];
#pragma unroll
    for (int bb = 0; bb < 16; ++bb) {
        float t1 = accl[bb] * (1.0f / 255.0f);
        t1b1[(size_t)(b0 + bb) * H_ + h] = t1 + bv;
        float u1 = accl[bb] + accr[bb] + 256.0f * bv;
        u1s[(size_t)(b0 + bb) * H_ + h] = f2bf(u1 * (1.0f / 255.0f));
    }
}

extern "C" void kernel_launch(void* const* d_in, const int* in_sizes, int n_in,
                              void* d_out, int out_size, void* d_ws, size_t ws_size,
                              hipStream_t stream)
{
    const float* x   = (const float*)d_in[0];
    const float* Wl1 = (const float*)d_in[1];
    const float* Wr1 = (const float*)d_in[2];
    const float* b1  = (const float*)d_in[3];
    const float* Wl2 = (const float*)d_in[4];
    const float* Wr2 = (const float*)d_in[5];
    const float* b2  = (const float*)d_in[6];
    const float* W1a = (const float*)d_in[7];
    const float* W1b = (const float*)d_in[8];
    const float* W2a = (const float*)d_in[9];
    const float* W2b = (const float*)d_in[10];
    float* out = (float*)d_out;

    char* ws = (char*)d_ws;
    size_t off = 0;
    auto alloc = [&](size_t bytes) -> char* {
        char* p = ws + off;
        off += (bytes + 255) & ~(size_t)255;
        return p;
    };

    const size_t BN = (size_t)B_ * N_;   // 32768
    const size_t BT = (size_t)B_ * T_;   // 65536

    u16* h_bf  = (u16*)alloc(BN * T_ * 2);
    u16* h1_bf = (u16*)alloc(BN * H_ * 2);
    u16* h2_bf = (u16*)alloc(BN * H_ * 2);
    u16* g_bf  = (u16*)alloc(BN * H_ * 2);
    u16* W1t   = (u16*)alloc((size_t)T_ * H_ * 2);
    u16* W2t   = (u16*)alloc((size_t)H_ * H_ * 2);
    u16* Wl2t  = (u16*)alloc((size_t)H_ * H_ * 2);
    u16* W1at  = (u16*)alloc((size_t)H_ * H_ * 2);
    u16* W1bt  = (u16*)alloc((size_t)T_ * H_ * 2);
    u16* W2at  = (u16*)alloc((size_t)N_ * N_ * 2);
    u16* W2bt  = (u16*)alloc((size_t)N_ * H_ * 2);
    float* s1   = (float*)alloc(BT * 4);
    float* t1b1 = (float*)alloc((size_t)B_ * H_ * 4);
    float* t2b2 = (float*)alloc((size_t)B_ * H_ * 4);
    u16*   u1s  = (u16*)alloc((size_t)B_ * H_ * 2);

    u16* p_bf = h_bf;
    u16* q_bf = h1_bf;
    u16* r_bf = h2_bf;

    dim3 blk32(32, 8);

    // prep
    k_tr_x<<<dim3(N_ / 32, T_ / 32, B_), blk32, 0, stream>>>(x, h_bf);
    k_rowsum<<<BT / 4, 256, 0, stream>>>(x, s1);
    k_combine_t<<<dim3(T_ / 32, H_ / 32), blk32, 0, stream>>>(Wr1, Wl1, W1t, T_, H_);
    k_combine_t<<<dim3(H_ / 32, H_ / 32), blk32, 0, stream>>>(Wr2, Wl2, W2t, H_, H_);
    k_combine_t<<<dim3(H_ / 32, H_ / 32), blk32, 0, stream>>>(Wl2, nullptr, Wl2t, H_, H_);
    k_combine_t<<<dim3(H_ / 32, H_ / 32), blk32, 0, stream>>>(W1a, nullptr, W1at, H_, H_);
    k_combine_t<<<dim3(H_ / 32, T_ / 32), blk32, 0, stream>>>(W1b, nullptr, W1bt, H_, T_);
    k_combine_t<<<dim3(N_ / 32, N_ / 32), blk32, 0, stream>>>(W2a, nullptr, W2at, N_, N_);
    k_combine_t<<<dim3(N_ / 32, H_ / 32), blk32, 0, stream>>>(W2b, nullptr, W2bt, N_, H_);
    k_vec1<<<dim3(H_ / 256, B_ / 16), 256, 0, stream>>>(s1, Wl1, Wr1, b1, t1b1, u1s);
    gemm_bt<0, 1><<<dim3(1, H_ / 128), 256, 0, stream>>>(u1s, Wl2t, t2b2, nullptr, b2, B_, H_, H_, 31);

    // main chain: gemm256, 1-D grid = (M/256)*(Nc/256), gysh = log2(Nc/256)
    gemm256<0, 0><<<dim3(128 * 4), 512, 0, stream>>>(h_bf,  W1t,  nullptr, h1_bf, t1b1,   H_, T_, 8, 2);
    gemm256<0, 0><<<dim3(128 * 4), 512, 0, stream>>>(h1_bf, W2t,  nullptr, h2_bf, t2b2,   H_, H_, 8, 2);
    gemm256<0, 0><<<dim3(128 * 4), 512, 0, stream>>>(h2_bf, W1at, nullptr, g_bf,  nullptr, H_, H_, 0, 2);
    gemm256<1, 0><<<dim3(128 * 2), 512, 0, stream>>>(g_bf,  W1bt, nullptr, p_bf,  nullptr, T_, H_, 0, 1);
    k_tr_p<<<dim3(T_ / 32, N_ / 32, B_), blk32, 0, stream>>>(p_bf, q_bf);
    gemm256<0, 0><<<dim3(256 * 1), 512, 0, stream>>>(q_bf,  W2at, nullptr, r_bf,  nullptr, N_, N_, 0, 0);
    gemm256<1, 1><<<dim3(256 * 4), 512, 0, stream>>>(r_bf,  W2bt, out,     nullptr, nullptr, H_, N_, 0, 2);
}

// Round 3
// 536.750 us; speedup vs baseline: 1.4361x; 1.2476x over previous
//
#include <hip/hip_runtime.h>
#include <hip/hip_bf16.h>

#define B_ 128
#define T_ 512
#define N_ 256
#define H_ 1024

typedef unsigned short u16;
typedef __attribute__((ext_vector_type(8))) __bf16 bf16x8;
typedef __attribute__((ext_vector_type(4))) float f32x4;

__device__ __forceinline__ u16 f2bf(float f) {
    unsigned u = __float_as_uint(f);
    u = (u + 0x7FFFu + ((u >> 16) & 1u)) >> 16;
    return (u16)u;
}

__device__ __forceinline__ void g2l16(const void* g, void* l) {
    __builtin_amdgcn_global_load_lds(
        (const __attribute__((address_space(1))) void*)g,
        (__attribute__((address_space(3))) void*)l,
        16, 0, 0);
}

// ===========================================================================
// 256x256-tile 8-wave phase-pipelined GEMM (T1+T2+T3+T4+T5). See R2 notes.
// OUT: 0 = bf16 row-major, 1 = f32 row-major, 2 = bf16 transposed q-write
//      (q[b, t=col, n=row&255], M-tile == one batch; sigmoid applied).
// ===========================================================================
#define LBUF 32768u
#define LMAT 16384u
#define LKS  8192u

#define BAR() { __builtin_amdgcn_s_barrier(); __builtin_amdgcn_sched_barrier(0); }
#define GATE(N) { asm volatile("s_waitcnt vmcnt(" #N ")" ::: "memory"); \
                  __builtin_amdgcn_s_barrier(); __builtin_amdgcn_sched_barrier(0); }
#define LD4(dst, base) { _Pragma("unroll") for (int i_ = 0; i_ < 4; ++i_) \
    dst[i_] = *(const bf16x8*)(L + (base) + i_ * 512); }
#define MF16(MB, RA, RB) { __builtin_amdgcn_s_setprio(1); \
    _Pragma("unroll") for (int mi_ = 0; mi_ < 4; ++mi_) \
    _Pragma("unroll") for (int ni_ = 0; ni_ < 4; ++ni_) \
        acc[(MB) + mi_][ni_] = __builtin_amdgcn_mfma_f32_16x16x32_bf16( \
            RA[mi_], RB[ni_], acc[(MB) + mi_][ni_], 0, 0, 0); \
    __builtin_amdgcn_s_setprio(0); }

template<int ACT, int OUT>
__global__ __launch_bounds__(512, 2) void gemm256(
    const u16* __restrict__ A, const u16* __restrict__ Bt,
    float* __restrict__ Cf, u16* __restrict__ Cb,
    const float* __restrict__ bias,
    int Nc, int K, int bshift, int gysh)
{
    __shared__ u16 L[65536];
    const int tid = threadIdx.x;
    const int wave = tid >> 6, lane = tid & 63;
    const int l16 = lane & 15, lh = lane >> 4;
    const int wm = wave >> 2, wn = wave & 3;

    const int qq = (int)gridDim.x >> 3;
    const int orig = (int)blockIdx.x;
    const int wg = (orig & 7) * qq + (orig >> 3);
    const int by = wg & ((1 << gysh) - 1), bx = wg >> gysh;
    const size_t m0 = (size_t)bx * 256, n0 = (size_t)by * 256;

    const int sx8 = (lh ^ ((l16 >> 1) & 3)) * 8;
    const unsigned aoff = (unsigned)(wm * 4096 + l16 * 32 + sx8);
    const unsigned boff = (unsigned)(LMAT + wn * 2048 + l16 * 32 + sx8);

    const int srow = tid >> 2;
    const int sslot = (tid & 3) ^ ((srow >> 1) & 3);
    const size_t jstr = (size_t)128 * K;
    const u16* gA = A + (m0 + srow) * (size_t)K + sslot * 8;
    const u16* gB = Bt + (n0 + srow) * (size_t)K + sslot * 8;
    u16* const dA0 = L + (unsigned)(wave * 512);
    u16* const dB0 = L + LMAT + (unsigned)(wave * 512);

    f32x4 acc[8][4] = {};
    const int nt = K >> 6;

    g2l16(gA, dA0);             g2l16(gA + jstr, dA0 + 4096);
    g2l16(gB, dB0);             g2l16(gB + jstr, dB0 + 4096);
    g2l16(gA + 32, dA0 + LKS);  g2l16(gA + 32 + jstr, dA0 + LKS + 4096);
    g2l16(gB + 32, dB0 + LKS);  g2l16(gB + 32 + jstr, dB0 + LKS + 4096);
    GATE(4);

    for (int t = 0; t < nt - 1; ++t) {
        const unsigned ab = (t & 1) ? LBUF : 0u;
        const unsigned an = ab ^ LBUF;
        const u16* gAt = gA + (size_t)(t + 1) * 64;
        const u16* gBt = gB + (size_t)(t + 1) * 64;
        bf16x8 ra[4], ra2[4], rb0r[4], rb1r[4];
        LD4(ra,   ab + aoff);
        LD4(rb0r, ab + boff);
        g2l16(gAt, dA0 + an);  g2l16(gAt + jstr, dA0 + an + 4096);
        BAR();
        MF16(0, ra, rb0r);
        BAR();
        LD4(ra2, ab + aoff + 2048);
        g2l16(gBt, dB0 + an);  g2l16(gBt + jstr, dB0 + an + 4096);
        BAR();
        MF16(4, ra2, rb0r);
        GATE(4);
        LD4(ra,   ab + LKS + aoff);
        LD4(rb1r, ab + LKS + boff);
        g2l16(gAt + 32, dA0 + an + LKS);  g2l16(gAt + 32 + jstr, dA0 + an + LKS + 4096);
        BAR();
        MF16(0, ra, rb1r);
        BAR();
        LD4(ra2, ab + LKS + aoff + 2048);
        g2l16(gBt + 32, dB0 + an + LKS);  g2l16(gBt + 32 + jstr, dB0 + an + LKS + 4096);
        BAR();
        MF16(4, ra2, rb1r);
        GATE(4);
    }

    {
        const unsigned ab = ((nt - 1) & 1) ? LBUF : 0u;
        bf16x8 ra[4], ra2[4], rb0r[4], rb1r[4];
        LD4(ra,   ab + aoff);
        LD4(rb0r, ab + boff);
        BAR();
        MF16(0, ra, rb0r);
        BAR();
        LD4(ra2, ab + aoff + 2048);
        BAR();
        MF16(4, ra2, rb0r);
        GATE(0);
        LD4(ra,   ab + LKS + aoff);
        LD4(rb1r, ab + LKS + boff);
        BAR();
        MF16(0, ra, rb1r);
        BAR();
        LD4(ra2, ab + LKS + aoff + 2048);
        BAR();
        MF16(4, ra2, rb1r);
    }

    const size_t NcS = (size_t)Nc;
#pragma unroll
    for (int mi = 0; mi < 8; ++mi) {
#pragma unroll
        for (int ni = 0; ni < 4; ++ni) {
            size_t rbase = m0 + wm * 128 + mi * 16 + lh * 4;
            size_t col   = n0 + wn * 64 + ni * 16 + l16;
            if (OUT == 2) {
                // q[b, t=col, n=rbase&255]; 4 consecutive n -> 8B store
                u16 e[4];
#pragma unroll
                for (int rr = 0; rr < 4; ++rr) {
                    float v = acc[mi][ni][rr];
                    v = 1.0f / (1.0f + __expf(-v));
                    e[rr] = f2bf(v);
                }
                size_t qi = ((rbase >> 8) * (size_t)T_ + col) * N_ + (rbase & 255);
                *(uint2*)(Cb + qi) = *(const uint2*)e;
            } else {
#pragma unroll
                for (int rr = 0; rr < 4; ++rr) {
                    size_t row = rbase + rr;
                    float v = acc[mi][ni][rr];
                    if (bias) v += bias[(row >> bshift) * NcS + col];
                    if (ACT) v = 1.0f / (1.0f + __expf(-v));
                    if (OUT == 1) Cf[row * NcS + col] = v;
                    else          Cb[row * NcS + col] = f2bf(v);
                }
            }
        }
    }
}

// ---------------------------------------------------------------------------
// 128x128 2-barrier GEMM for the small prep GEMMs.
// C = act( (A @ Bt^T) * kscale + bmul * bias )
// ---------------------------------------------------------------------------
template<int ACT, int OUTF32>
__global__ __launch_bounds__(256) void gemm_bt(
    const u16* __restrict__ A, const u16* __restrict__ Bt,
    float* __restrict__ Cf, u16* __restrict__ Cb,
    const float* __restrict__ bias,
    int M, int Nc, int K, int bshift, float kscale, float bmul)
{
    __shared__ u16 lA[128 * 64];
    __shared__ u16 lB[128 * 64];
    const int tid = threadIdx.x;
    const int wave = tid >> 6, lane = tid & 63;
    const int l16 = lane & 15, lh = lane >> 4;
    const int wm = wave >> 1, wn = wave & 1;
    const long m0 = (long)blockIdx.x * 128;
    const long n0 = (long)blockIdx.y * 128;

    f32x4 acc[4][4] = {};

    for (int k0 = 0; k0 < K; k0 += 64) {
#pragma unroll
        for (int j = 0; j < 4; ++j) {
            int c = j * 256 + tid;
            int row = c >> 3, col = (c & 7) << 3;
            g2l16(A  + (m0 + row) * (size_t)K + k0 + col, &lA[(size_t)(j * 256 + (wave << 6)) * 8]);
            g2l16(Bt + (n0 + row) * (size_t)K + k0 + col, &lB[(size_t)(j * 256 + (wave << 6)) * 8]);
        }
        __syncthreads();
#pragma unroll
        for (int s = 0; s < 2; ++s) {
            bf16x8 af[4], bfr[4];
#pragma unroll
            for (int mi = 0; mi < 4; ++mi)
                af[mi] = *(const bf16x8*)&lA[((wm << 6) + (mi << 4) + l16) * 64 + s * 32 + (lh << 3)];
#pragma unroll
            for (int ni = 0; ni < 4; ++ni)
                bfr[ni] = *(const bf16x8*)&lB[((wn << 6) + (ni << 4) + l16) * 64 + s * 32 + (lh << 3)];
#pragma unroll
            for (int mi = 0; mi < 4; ++mi)
#pragma unroll
                for (int ni = 0; ni < 4; ++ni)
                    acc[mi][ni] = __builtin_amdgcn_mfma_f32_16x16x32_bf16(af[mi], bfr[ni], acc[mi][ni], 0, 0, 0);
        }
        __syncthreads();
    }

#pragma unroll
    for (int mi = 0; mi < 4; ++mi) {
#pragma unroll
        for (int ni = 0; ni < 4; ++ni) {
            long rbase = m0 + (wm << 6) + (mi << 4) + (lh << 2);
            long col   = n0 + (wn << 6) + (ni << 4) + l16;
#pragma unroll
            for (int r = 0; r < 4; ++r) {
                long row = rbase + r;
                float v = acc[mi][ni][r] * kscale;
                if (bias) v += bmul * bias[(size_t)(row >> bshift) * Nc + col];
                if (ACT) v = 1.0f / (1.0f + __expf(-v));
                if (OUTF32) Cf[(size_t)row * Nc + col] = v;
                else        Cb[(size_t)row * Nc + col] = f2bf(v);
            }
        }
    }
}

// x[B,T,N] f32 -> h[B,N,T] bf16 transpose + per-(b,t) rowsum (fused, one x read)
// block: 256 threads, covers 32 t-rows x 256 n of one batch.
__global__ __launch_bounds__(256) void k_trx_rs(
    const float* __restrict__ x, u16* __restrict__ h, u16* __restrict__ s1b)
{
    __shared__ float sm[32][257];
    const int b = blockIdx.y, t0 = blockIdx.x * 32;
    const int tid = threadIdx.x;
    const float* xb = x + ((size_t)b * T_ + t0) * N_;
#pragma unroll 8
    for (int j = 0; j < 32; ++j)
        sm[j][tid] = xb[(size_t)j * N_ + tid];
    __syncthreads();
    // rowsum: wave w reduces rows 8w..8w+7
    const int wave = tid >> 6, lane = tid & 63;
#pragma unroll
    for (int i = 0; i < 8; ++i) {
        int j = wave * 8 + i;
        float s = sm[j][lane] + sm[j][lane + 64] + sm[j][lane + 128] + sm[j][lane + 192];
#pragma unroll
        for (int o = 32; o; o >>= 1) s += __shfl_down(s, o, 64);
        if (lane == 0) s1b[(size_t)b * T_ + t0 + j] = f2bf(s);
    }
    // transpose write: thread n -> h[b, n, t0..t0+31] (64 B contiguous)
    u16 e[32];
#pragma unroll
    for (int j = 0; j < 32; ++j) e[j] = f2bf(sm[j][tid]);
    uint4* dst = (uint4*)(h + ((size_t)b * N_ + tid) * T_ + t0);
    const uint4* src = (const uint4*)e;
#pragma unroll
    for (int v = 0; v < 4; ++v) dst[v] = src[v];
}

// Wl1,Wr1 [512,1024] -> W1t=(Wr1-Wl1/255)^T, Wl1t=Wl1^T, Wlr1t=(Wl1+Wr1)^T  [1024,512]
__global__ void k_tr3(const float* __restrict__ Wl, const float* __restrict__ Wr,
                      u16* __restrict__ W1t, u16* __restrict__ Wl1t, u16* __restrict__ Wlr1t)
{
    __shared__ float tl[32][33], tr[32][33];
    int r0 = blockIdx.x * 32, c0 = blockIdx.y * 32;
    int tx = threadIdx.x, ty = threadIdx.y;
#pragma unroll
    for (int i = 0; i < 4; ++i) {
        int r = r0 + ty + 8 * i;
        tl[ty + 8 * i][tx] = Wl[(size_t)r * H_ + c0 + tx];
        tr[ty + 8 * i][tx] = Wr[(size_t)r * H_ + c0 + tx];
    }
    __syncthreads();
#pragma unroll
    for (int i = 0; i < 4; ++i) {
        int c = c0 + ty + 8 * i;
        float wl = tl[tx][ty + 8 * i], wr = tr[tx][ty + 8 * i];
        size_t o = (size_t)c * T_ + r0 + tx;
        W1t[o]   = f2bf(wr - wl * (1.0f / 255.0f));
        Wl1t[o]  = f2bf(wl);
        Wlr1t[o] = f2bf(wl + wr);
    }
}

// Wl2,Wr2 [1024,1024] -> W2t=(Wr2-Wl2/255)^T, Wl2t=Wl2^T  [1024,1024]
__global__ void k_tr2(const float* __restrict__ Wl, const float* __restrict__ Wr,
                      u16* __restrict__ W2t, u16* __restrict__ Wl2t)
{
    __shared__ float tl[32][33], tr[32][33];
    int r0 = blockIdx.x * 32, c0 = blockIdx.y * 32;
    int tx = threadIdx.x, ty = threadIdx.y;
#pragma unroll
    for (int i = 0; i < 4; ++i) {
        int r = r0 + ty + 8 * i;
        tl[ty + 8 * i][tx] = Wl[(size_t)r * H_ + c0 + tx];
        tr[ty + 8 * i][tx] = Wr[(size_t)r * H_ + c0 + tx];
    }
    __syncthreads();
#pragma unroll
    for (int i = 0; i < 4; ++i) {
        int c = c0 + ty + 8 * i;
        float wl = tl[tx][ty + 8 * i], wr = tr[tx][ty + 8 * i];
        size_t o = (size_t)c * H_ + r0 + tx;
        W2t[o]  = f2bf(wr - wl * (1.0f / 255.0f));
        Wl2t[o] = f2bf(wl);
    }
}

// Wt[c][r] = bf16(W[r][c])  (plain transpose-cast)
__global__ void k_trc(const float* __restrict__ W, u16* __restrict__ Wt, int R, int C) {
    __shared__ float tile[32][33];
    int r0 = blockIdx.x * 32, c0 = blockIdx.y * 32;
    int tx = threadIdx.x, ty = threadIdx.y;
#pragma unroll
    for (int i = 0; i < 4; ++i)
        tile[ty + 8 * i][tx] = W[(size_t)(r0 + ty + 8 * i) * C + c0 + tx];
    __syncthreads();
#pragma unroll
    for (int i = 0; i < 4; ++i)
        Wt[(size_t)(c0 + ty + 8 * i) * R + r0 + tx] = f2bf(tile[tx][ty + 8 * i]);
}

// f32 -> bf16 cast, 8 elems/thread
__global__ void k_cast(const float* __restrict__ s, u16* __restrict__ d, int n8) {
    int i = blockIdx.x * 256 + threadIdx.x;
    if (i < n8) {
        float4 a = ((const float4*)s)[2 * i], b = ((const float4*)s)[2 * i + 1];
        u16 e[8] = {f2bf(a.x), f2bf(a.y), f2bf(a.z), f2bf(a.w),
                    f2bf(b.x), f2bf(b.y), f2bf(b.z), f2bf(b.w)};
        ((uint4*)d)[i] = *(const uint4*)e;
    }
}

extern "C" void kernel_launch(void* const* d_in, const int* in_sizes, int n_in,
                              void* d_out, int out_size, void* d_ws, size_t ws_size,
                              hipStream_t stream)
{
    const float* x   = (const float*)d_in[0];
    const float* Wl1 = (const float*)d_in[1];
    const float* Wr1 = (const float*)d_in[2];
    const float* b1  = (const float*)d_in[3];
    const float* Wl2 = (const float*)d_in[4];
    const float* Wr2 = (const float*)d_in[5];
    const float* b2  = (const float*)d_in[6];
    const float* W1a = (const float*)d_in[7];
    const float* W1b = (const float*)d_in[8];
    const float* W2a = (const float*)d_in[9];
    const float* W2b = (const float*)d_in[10];
    float* out = (float*)d_out;

    char* ws = (char*)d_ws;
    size_t off = 0;
    auto alloc = [&](size_t bytes) -> char* {
        char* p = ws + off;
        off += (bytes + 255) & ~(size_t)255;
        return p;
    };

    const size_t BN = (size_t)B_ * N_;   // 32768
    const size_t BT = (size_t)B_ * T_;   // 65536

    u16* h_bf   = (u16*)alloc(BN * T_ * 2);        // 33.5MB; reused as q after G1
    u16* h1_bf  = (u16*)alloc(BN * H_ * 2);        // 67MB
    u16* h2_bf  = (u16*)alloc(BN * H_ * 2);        // 67MB
    u16* W1t    = (u16*)alloc((size_t)H_ * T_ * 2);
    u16* Wl1t   = (u16*)alloc((size_t)H_ * T_ * 2);
    u16* Wlr1t  = (u16*)alloc((size_t)H_ * T_ * 2);
    u16* W2t    = (u16*)alloc((size_t)H_ * H_ * 2);
    u16* Wl2t   = (u16*)alloc((size_t)H_ * H_ * 2);
    u16* W1bt   = (u16*)alloc((size_t)T_ * H_ * 2);  // [512,1024]
    u16* W1ab   = (u16*)alloc((size_t)H_ * H_ * 2);  // bf16(W1a)
    u16* W1ct   = (u16*)alloc((size_t)T_ * H_ * 2);  // (W1a@W1b)^T  [512,1024]
    u16* W2bt   = (u16*)alloc((size_t)H_ * N_ * 2);  // [1024,256]
    u16* W2ab   = (u16*)alloc((size_t)N_ * N_ * 2);  // bf16(W2a)
    u16* W2ct   = (u16*)alloc((size_t)H_ * N_ * 2);  // (W2a@W2b)^T  [1024,256]
    u16* s1b    = (u16*)alloc(BT * 2);
    float* t1b1 = (float*)alloc((size_t)B_ * H_ * 4);
    float* t2b2 = (float*)alloc((size_t)B_ * H_ * 4);
    u16*   u1s  = (u16*)alloc((size_t)B_ * H_ * 2);

    u16* q_bf = h_bf;   // [B,T,N], h dead after G1... (written by G4' after G2/G4 read h2)

    dim3 blk32(32, 8);

    // --- prep (x transpose + rowsum fused; weight transforms) ---
    k_trx_rs<<<dim3(T_ / 32, B_), 256, 0, stream>>>(x, h_bf, s1b);
    k_tr3<<<dim3(T_ / 32, H_ / 32), blk32, 0, stream>>>(Wl1, Wr1, W1t, Wl1t, Wlr1t);
    k_tr2<<<dim3(H_ / 32, H_ / 32), blk32, 0, stream>>>(Wl2, Wr2, W2t, Wl2t);
    k_trc<<<dim3(H_ / 32, T_ / 32), blk32, 0, stream>>>(W1b, W1bt, H_, T_);
    k_trc<<<dim3(N_ / 32, H_ / 32), blk32, 0, stream>>>(W2b, W2bt, N_, H_);
    k_cast<<<dim3(H_ * H_ / 2048), 256, 0, stream>>>(W1a, W1ab, H_ * H_ / 8);
    k_cast<<<dim3(N_ * N_ / 2048), 256, 0, stream>>>(W2a, W2ab, N_ * N_ / 8);

    // rank-1 SAGE terms as tiny GEMMs:
    // t1b1 = s1@Wl1/255 + b1 ; u1s = bf16((s1@(Wl1+Wr1) + 256*b1)/255)
    gemm_bt<0, 1><<<dim3(1, H_ / 128), 256, 0, stream>>>(s1b, Wl1t,  t1b1, nullptr, b1, B_, H_, T_, 31, 1.0f / 255.0f, 1.0f);
    gemm_bt<0, 0><<<dim3(1, H_ / 128), 256, 0, stream>>>(s1b, Wlr1t, nullptr, u1s,  b1, B_, H_, T_, 31, 1.0f / 255.0f, 256.0f / 255.0f);
    // t2b2 = u1s @ Wl2 + b2
    gemm_bt<0, 1><<<dim3(1, H_ / 128), 256, 0, stream>>>(u1s, Wl2t, t2b2, nullptr, b2, B_, H_, H_, 31, 1.0f, 1.0f);
    // collapsed block weights: W1ct[t,h] = (W1a@W1b)[h,t] ; W2ct[h,n'] = (W2a@W2b)[n',h]
    gemm_bt<0, 0><<<dim3(T_ / 128, H_ / 128), 256, 0, stream>>>(W1bt, W1ab, nullptr, W1ct, nullptr, T_, H_, H_, 0, 1.0f, 0.0f);
    gemm_bt<0, 0><<<dim3(H_ / 128, N_ / 128), 256, 0, stream>>>(W2bt, W2ab, nullptr, W2ct, nullptr, H_, N_, N_, 0, 1.0f, 0.0f);

    // --- main chain (4 big GEMMs) ---
    // G1: h1 = h @ W1' + t1b1          [32768,1024] K=512
    gemm256<0, 0><<<dim3(128 * 4), 512, 0, stream>>>(h_bf, W1t, nullptr, h1_bf, t1b1, H_, T_, 8, 2);
    // G2: h2 = h1 @ W2' + t2b2         [32768,1024] K=1024
    gemm256<0, 0><<<dim3(128 * 4), 512, 0, stream>>>(h1_bf, W2t, nullptr, h2_bf, t2b2, H_, H_, 8, 2);
    // G4': q = sigma(h2 @ W1c) written transposed as q[B,T,N]   K=1024
    gemm256<1, 2><<<dim3(128 * 2), 512, 0, stream>>>(h2_bf, W1ct, nullptr, q_bf, nullptr, T_, H_, 0, 1);
    // G7': out = sigma(q @ W2c)  f32   [65536,1024] K=256
    gemm256<1, 1><<<dim3(256 * 4), 512, 0, stream>>>(q_bf, W2ct, out, nullptr, nullptr, H_, N_, 0, 2);
}